// Round 8
// baseline (142.350 us; speedup 1.0000x reference)
//
#include <hip/hip_runtime.h>

// Terrain3D — gather formulation; compacted per-tile particle data (no list
// indirection), emotions via scalar loads, ky/kz 4-batched b128 LDS reads.
// ws layout (floats): [0, 5*G3) = H,E grids; then int counts[NTILES];
// then float4 tileG[NTILES*CAP]; then float4 tileEm[NTILES*CAP].

namespace {
constexpr int   G      = 128;
constexpr int   G3     = G * G * G;
constexpr int   NE     = 4;
constexpr int   RAD    = 9;            // max(2, int(3*0.05*128/2)) = 9
constexpr float SIG    = 0.05f * (float)G * 0.5f;  // 3.2
constexpr float INV2S2 = 1.0f / (2.0f * SIG * SIG);
constexpr float ETA    = 0.01f;
constexpr float A_H    = 0.002f;
constexpr float A_E    = 0.001f;
constexpr float LEAK   = 5e-5f;

// tile geometry: 8 x 8 x 16 voxels. 256 threads; thread owns 4 axis0 voxels
// i = (tid>>7) + {0,2,4,6} at its (j = (tid>>4)&7, k = tid&15).
constexpr int T0 = 8, T1 = 8, T2 = 16;
constexpr int NT0 = G / T0, NT1 = G / T1, NT2 = G / T2;   // 16, 16, 8
constexpr int NTILES = NT0 * NT1 * NT2;                   // 2048
constexpr int CAP = 96;   // interior-tile mean ~45; P(>96) negligible
constexpr int PAD = 100;  // SoA stride for ky/kz (mult of 4; staggered banks)
}

__device__ __forceinline__ int clampi(int v, int lo, int hi) {
    return min(max(v, lo), hi);
}

// ---------------------------------------------------------------------------
// 0) zero the tile counts (replaces hipMemsetAsync fill dispatch)
// ---------------------------------------------------------------------------
__global__ void zero_counts(int4* __restrict__ counts4) {
    counts4[threadIdx.x + blockIdx.x * blockDim.x] = make_int4(0, 0, 0, 0);
}

// ---------------------------------------------------------------------------
// 1) bin: one WAVE per particle. Writes the particle's {g,omega} and emotions
//    COMPACTED per tile, so the gather kernel needs no indirection.
//    First 48 lanes cover the 4x4x3 candidate-tile grid of the bbox.
// ---------------------------------------------------------------------------
__global__ void __launch_bounds__(256) bin_kernel(
        const float* __restrict__ pos, const float* __restrict__ inten,
        const float4* __restrict__ emo4,
        int* __restrict__ counts,
        float4* __restrict__ tileG, float4* __restrict__ tileEm, int N) {
    const int p    = blockIdx.x * 4 + (threadIdx.x >> 6);
    const int lane = threadIdx.x & 63;
    if (p >= N) return;

    const float gx = (pos[p * 3 + 0] + 1.0f) * 0.5f * (float)(G - 1);
    const float gy = (pos[p * 3 + 1] + 1.0f) * 0.5f * (float)(G - 1);
    const float gz = (pos[p * 3 + 2] + 1.0f) * 0.5f * (float)(G - 1);
    const int c0 = clampi((int)floorf(gx), 0, G - 1);
    const int c1 = clampi((int)floorf(gy), 0, G - 1);
    const int c2 = clampi((int)floorf(gz), 0, G - 1);

    const int l0 = max(c0 - RAD, 0) >> 3, h0 = min(c0 + RAD, G - 1) >> 3;
    const int l1 = max(c1 - RAD, 0) >> 3, h1 = min(c1 + RAD, G - 1) >> 3;
    const int l2 = max(c2 - RAD, 0) >> 4, h2 = min(c2 + RAD, G - 1) >> 4;
    const int n0 = h0 - l0, n1 = h1 - l1, n2 = h2 - l2;  // inclusive spans - 1

    if (lane < 48) {                    // fixed 4x4x3 slot grid, single pass
        const int a  = lane / 12;       // 0..3
        const int r  = lane - a * 12;
        const int b  = r / 3;           // 0..3
        const int cs = r - b * 3;       // 0..2
        if (a <= n0 && b <= n1 && cs <= n2) {
            const int t = ((l0 + a) * NT1 + (l1 + b)) * NT2 + (l2 + cs);
            const int slot = atomicAdd(&counts[t], 1);
            if (slot < CAP) {
                const size_t idx = (size_t)t * CAP + slot;
                tileG[idx]  = make_float4(gx, gy, gz, inten[p] * ETA);
                tileEm[idx] = emo4[p];
            }
        }
    }
}

// ---------------------------------------------------------------------------
// 2) gather: one block per tile. Phase 1: thread n builds particle n's
//    separable tables (kx AoS float4x2 w/ omega folded; ky/kz SoA stride PAD).
//    ONE barrier. Phase 2: per 4 particles: 1 b128 ky + 1 b128 kz; per
//    particle: 1 broadcast b128 kx + scalar-load emotions (not LDS!) +
//    ~26 VALU for 20 accumulators.
// ---------------------------------------------------------------------------
__global__ void __launch_bounds__(256) gather_kernel(
        const float4* __restrict__ tileG, const float4* __restrict__ tileEm,
        const float* __restrict__ H0, const float* __restrict__ E0,
        const int* __restrict__ counts, float* __restrict__ ws) {
    const int tile = blockIdx.x;
    const int cnt  = min(counts[tile], CAP);
    const int t2 = tile & 7, t1 = (tile >> 3) & 15, t0 = tile >> 7;
    const int tid = threadIdx.x;

    __shared__ __align__(16) float kxf[CAP * 8];   // AoS: n*8 + iA*4 + ii
    __shared__ __align__(16) float kyf[8 * PAD];   // SoA: j*PAD + n
    __shared__ __align__(16) float kzf[16 * PAD];  // SoA: k*PAD + n

    const int b0 = t0 * T0, b1 = t1 * T1, b2 = t2 * T2;

    // ---- per-thread voxels: i = iA + {0,2,4,6} at (j, k) ----
    const int k  = tid & 15;           // axis2
    const int j  = (tid >> 4) & 7;     // axis1
    const int iA = tid >> 7;           // 0/1
    const int x2 = b2 + k, x1 = b1 + j;
    const int flat0 = ((b0 + iA) * G + x1) * G + x2;   // i step = 2*G*G

    // issue init loads FIRST — latency hides under phase 1
    float h[4], e[NE][4];
#pragma unroll
    for (int i = 0; i < 4; ++i) {
        h[i] = H0[flat0 + i * 2 * G * G];
#pragma unroll
        for (int c = 0; c < NE; ++c)
            e[c][i] = E0[c * G3 + flat0 + i * 2 * G * G];
    }

    const int padded = (cnt + 15) & ~15;

    // ---- phase 1: thread n builds particle n's table ----
    if (tid < padded) {
        float4* kx4w = (float4*)kxf;
        if (tid < cnt) {
            const float4 mg = tileG[(size_t)tile * CAP + tid];  // coalesced
            const int cx = clampi((int)floorf(mg.x), 0, G - 1);
            const int cy = clampi((int)floorf(mg.y), 0, G - 1);
            const int cz = clampi((int)floorf(mg.z), 0, G - 1);

            float4 kxa, kxb;
            {
                float* a = &kxa.x;
                float* b = &kxb.x;
#pragma unroll
                for (int ii = 0; ii < 4; ++ii) {
                    const int c0a = b0 + 2 * ii;       // iA = 0
                    const int c0b = b0 + 1 + 2 * ii;   // iA = 1
                    const float da = (float)c0a - mg.x;
                    const float db = (float)c0b - mg.x;
                    a[ii] = (abs(c0a - cx) <= RAD)
                          ? __expf(-da * da * INV2S2) * mg.w : 0.0f;
                    b[ii] = (abs(c0b - cx) <= RAD)
                          ? __expf(-db * db * INV2S2) * mg.w : 0.0f;
                }
            }
            kx4w[tid * 2 + 0] = kxa;
            kx4w[tid * 2 + 1] = kxb;

#pragma unroll
            for (int off = 0; off < 8; ++off) {
                const int coord = b1 + off;
                const float d = (float)coord - mg.y;
                kyf[off * PAD + tid] = (abs(coord - cy) <= RAD)
                                     ? __expf(-d * d * INV2S2) : 0.0f;
            }
#pragma unroll
            for (int off = 0; off < 16; ++off) {
                const int coord = b2 + off;
                const float d = (float)coord - mg.z;
                kzf[off * PAD + tid] = (abs(coord - cz) <= RAD)
                                     ? __expf(-d * d * INV2S2) : 0.0f;
            }
        } else {
            const float4 z4 = make_float4(0.f, 0.f, 0.f, 0.f);
            kx4w[tid * 2 + 0] = z4;    // zero weight kills pad FMAs
            kx4w[tid * 2 + 1] = z4;
#pragma unroll
            for (int off = 0; off < 8; ++off)  kyf[off * PAD + tid] = 0.0f;
#pragma unroll
            for (int off = 0; off < 16; ++off) kzf[off * PAD + tid] = 0.0f;
        }
    }
    __syncthreads();

    // ---- phase 2: 1.5 DS instr / particle; emotions via scalar loads ----
    const float4* __restrict__ kx4 = (const float4*)kxf;
    const float4* __restrict__ emp = tileEm + (size_t)tile * CAP;  // uniform
    const float*  __restrict__ kyp = kyf + j * PAD;
    const float*  __restrict__ kzp = kzf + k * PAD;

    for (int base = 0; base < padded; base += 16) {
#pragma unroll
        for (int q = 0; q < 4; ++q) {
            const int n4 = base + q * 4;
            const float4 ky4 = *(const float4*)(kyp + n4);  // 4 particles
            const float4 kz4 = *(const float4*)(kzp + n4);
            const float kyu[4] = {ky4.x, ky4.y, ky4.z, ky4.w};
            const float kzu[4] = {kz4.x, kz4.y, kz4.z, kz4.w};
#pragma unroll
            for (int u = 0; u < 4; ++u) {
                const int n = n4 + u;
                const float4 kxv = kx4[n * 2 + iA];  // b128 broadcast
                const float4 emv = emp[n];           // s_load_dwordx4 (uniform)
                const float kyz = kyu[u] * kzu[u];
                const float w0 = kxv.x * kyz, w1 = kxv.y * kyz;
                const float w2 = kxv.z * kyz, w3 = kxv.w * kyz;
                h[0] += w0;  h[1] += w1;  h[2] += w2;  h[3] += w3;
                e[0][0] += w0 * emv.x; e[0][1] += w1 * emv.x; e[0][2] += w2 * emv.x; e[0][3] += w3 * emv.x;
                e[1][0] += w0 * emv.y; e[1][1] += w1 * emv.y; e[1][2] += w2 * emv.y; e[1][3] += w3 * emv.y;
                e[2][0] += w0 * emv.z; e[2][1] += w1 * emv.z; e[2][2] += w2 * emv.z; e[2][3] += w3 * emv.z;
                e[3][0] += w0 * emv.w; e[3][1] += w1 * emv.w; e[3][2] += w2 * emv.w; e[3][3] += w3 * emv.w;
            }
        }
    }

#pragma unroll
    for (int i = 0; i < 4; ++i) {
        ws[flat0 + i * 2 * G * G] = h[i];
#pragma unroll
        for (int c = 0; c < NE; ++c)
            ws[(c + 1) * G3 + flat0 + i * 2 * G * G] = e[c][i];
    }
}

// ---------------------------------------------------------------------------
// 3) fused step (leak + alpha*laplacian + relu) + trilinear sample.
//    8-way corner parallelism + shuffle reduction.
//    NOTE reference transpose: splat flattens (c0*G+c1)*G+c2 but sampling
//    reads vol[comp2][comp1][comp0] -> flat = comp2*G^2 + comp1*G + comp0.
// ---------------------------------------------------------------------------
__device__ __forceinline__ float stepped_at(const float* __restrict__ vol,
                                            int z, int y, int x,
                                            float addc, float alpha) {
    const int zm = max(z - 1, 0), zp = min(z + 1, G - 1);
    const int ym = max(y - 1, 0), yp = min(y + 1, G - 1);
    const int xm = max(x - 1, 0), xp = min(x + 1, G - 1);
    const float cv  = vol[(z * G + y) * G + x];
    const float lap = vol[(zm * G + y) * G + x] + vol[(zp * G + y) * G + x]
                    + vol[(z * G + ym) * G + x] + vol[(z * G + yp) * G + x]
                    + vol[(z * G + y) * G + xm] + vol[(z * G + y) * G + xp]
                    - 6.0f * cv;
    const float s = cv * (1.0f - LEAK) + addc + alpha * lap;
    return fmaxf(s, 0.0f);
}

__global__ void __launch_bounds__(256) sample_kernel(
        const float* __restrict__ sp, const float* __restrict__ ws,
        float* __restrict__ out, int n_out) {
    const int gt = blockIdx.x * blockDim.x + threadIdx.x;
    const int corner = gt & 7;
    const int o = gt >> 3;
    if (o >= n_out) return;
    const int c = o % 5;   // 0 = H, 1..4 = E
    const int p = o / 5;

    const float t0 = fminf(fmaxf((sp[p * 3 + 0] + 1.0f) * 0.5f * (float)(G - 1), 0.0f), (float)(G - 1));
    const float t1 = fminf(fmaxf((sp[p * 3 + 1] + 1.0f) * 0.5f * (float)(G - 1), 0.0f), (float)(G - 1));
    const float t2 = fminf(fmaxf((sp[p * 3 + 2] + 1.0f) * 0.5f * (float)(G - 1), 0.0f), (float)(G - 1));

    const int a0 = (int)floorf(t0);  const float f0 = t0 - (float)a0;
    const int a1 = (int)floorf(t1);  const float f1 = t1 - (float)a1;
    const int a2 = (int)floorf(t2);  const float f2 = t2 - (float)a2;
    const int b0 = min(a0 + 1, G - 1);
    const int b1 = min(a1 + 1, G - 1);
    const int b2 = min(a2 + 1, G - 1);

    const int d0 = corner & 1, d1 = (corner >> 1) & 1, d2 = corner >> 2;
    const int   x = d0 ? b0 : a0;          // comp0 -> fastest axis
    const int   y = d1 ? b1 : a1;          // comp1
    const int   z = d2 ? b2 : a2;          // comp2 -> slowest axis
    const float w = (d0 ? f0 : 1.0f - f0) * (d1 ? f1 : 1.0f - f1)
                  * (d2 ? f2 : 1.0f - f2);

    const float* vol  = ws + (size_t)c * G3;
    const float addc  = (c == 0) ? 0.0f : LEAK;
    const float alpha = (c == 0) ? A_H : A_E;

    float v = w * stepped_at(vol, z, y, x, addc, alpha);
    v += __shfl_xor(v, 1);
    v += __shfl_xor(v, 2);
    v += __shfl_xor(v, 4);
    if (corner == 0) out[o] = v;
}

// ---------------------------------------------------------------------------
extern "C" void kernel_launch(void* const* d_in, const int* in_sizes, int n_in,
                              void* d_out, int out_size, void* d_ws, size_t ws_size,
                              hipStream_t stream) {
    const float* positions   = (const float*)d_in[0];  // (N,3)
    const float* intensities = (const float*)d_in[1];  // (N,)
    const float* emotions    = (const float*)d_in[2];  // (N,4)
    const float* sample_pos  = (const float*)d_in[3];  // (B,T,3)
    const float* H0          = (const float*)d_in[4];  // (G,G,G)
    const float* E0          = (const float*)d_in[5];  // (4,G,G,G)
    float* ws  = (float*)d_ws;
    float* out = (float*)d_out;

    const int N = in_sizes[0] / 3;

    int*    counts = (int*)(ws + 5 * (size_t)G3);
    float4* tileG  = (float4*)(counts + NTILES);          // NTILES*CAP float4
    float4* tileEm = tileG + (size_t)NTILES * CAP;

    zero_counts<<<2, 256, 0, stream>>>((int4*)counts);    // 2048 ints

    bin_kernel<<<(N + 3) / 4, 256, 0, stream>>>(
        positions, intensities, (const float4*)emotions,
        counts, tileG, tileEm, N);

    gather_kernel<<<NTILES, 256, 0, stream>>>(
        tileG, tileEm, H0, E0, counts, ws);

    const int n_thr = out_size * 8;
    sample_kernel<<<(n_thr + 255) / 256, 256, 0, stream>>>(
        sample_pos, ws, out, out_size);
}